// Round 5
// baseline (18858.208 us; speedup 1.0000x reference)
//
#include <hip/hip_runtime.h>
#include <hip/hip_bf16.h>

#define T_LEN 4096
#define HID   512
#define EMB   256
#define KTAG  16
#define START_TAG 14
#define END_TAG   15
#define NEGV  (-10000.0f)
#define NTEAM   32   // elected team: 16 WGs per direction
#define NLAUNCH 256  // 1 block/CU; argmax XCD holds >= 32 by pigeonhole

// elect[] int indices
#define E_CENSUS 0   // 0..7
#define E_ARRIVE 8
#define E_CHOSEN 9
#define E_CLAIM  10
#define E_VOTE   12
#define E_XCC    16  // 16..47: per-slot xcc+1

typedef __attribute__((ext_vector_type(4))) unsigned int uint4v;

__device__ __forceinline__ unsigned long long packph(float h, unsigned tag) {
  return ((unsigned long long)tag << 32) | (unsigned long long)__float_as_uint(h);
}

// ---- sc0 (XCD-L2 scope) ops: L1-bypass, served by the XCD-shared L2 ----
__device__ __forceinline__ void issue_ld4_sc0(const unsigned long long* p, uint4v& d) {
  asm volatile("global_load_dwordx4 %0, %1, off sc0" : "=&v"(d) : "v"(p));
}
__device__ __forceinline__ void wait_ld(uint4v& d) {
  asm volatile("s_waitcnt vmcnt(0)" : "+v"(d) :: "memory");
}
__device__ __forceinline__ void st_pair_sc0(unsigned long long* p, unsigned long long v) {
  asm volatile("global_store_dwordx2 %0, %1, off sc0" :: "v"(p), "v"(v) : "memory");
}
// ---- agent-scope ops (round-3 proven fallback) ----
__device__ __forceinline__ unsigned long long ld_pair_agent(const unsigned long long* p) {
  return __hip_atomic_load(p, __ATOMIC_RELAXED, __HIP_MEMORY_SCOPE_AGENT);
}
__device__ __forceinline__ void st_pair_agent(unsigned long long* p, unsigned long long v) {
  __hip_atomic_store(p, v, __ATOMIC_RELAXED, __HIP_MEMORY_SCOPE_AGENT);
}

// ---------------------------------------------------------------------------
// Main recurrence body. Team of 32 WGs; WG slot s: dir=s>>4, owns comps
// [32*(s&15), +32). Wave w = k-quarter; lane l handles rows (gate=l>>4,
// j=(l&15)) and (gate, (l&15)+16): 384 weight f32 in registers. Per step:
// poll own 128-comp chunk (2 tagged pairs/lane) -> LDS -> FMA -> one
// __syncthreads -> wave0 reduce/activation -> publish 32-pair burst.
// ---------------------------------------------------------------------------
template<int FAST>
__device__ void lstm_body(
    const float* __restrict__ Whh, const float* __restrict__ Wih,
    const float* __restrict__ bb,  const float* __restrict__ c0,
    const int*   __restrict__ x,   const float* __restrict__ embed,
    unsigned long long* __restrict__ pb, float* __restrict__ hOut,
    int dir, int sl, int w, int l)
{
  const int J0   = sl * 32;
  const int jl   = l & 15;
  const int gate = l >> 4;
  const int r0   = gate * HID + J0 + jl;
  const int r1   = r0 + 16;

  float wh0[128], wh1[128], we0[64], we1[64];
  {
    const float* p0 = Whh + (size_t)r0 * HID + w * 128;
    const float* p1 = Whh + (size_t)r1 * HID + w * 128;
    #pragma unroll
    for (int i = 0; i < 32; ++i) {
      *(float4*)&wh0[i*4] = *(const float4*)&p0[i*4];
      *(float4*)&wh1[i*4] = *(const float4*)&p1[i*4];
    }
    const float* q0 = Wih + (size_t)r0 * EMB + w * 64;
    const float* q1 = Wih + (size_t)r1 * EMB + w * 64;
    #pragma unroll
    for (int i = 0; i < 16; ++i) {
      *(float4*)&we0[i*4] = *(const float4*)&q0[i*4];
      *(float4*)&we1[i*4] = *(const float4*)&q1[i*4];
    }
  }
  // activation-lane constants (wave0 lanes 0..31 use them)
  const int ac = J0 + (l & 31);
  const float bi = bb[ac], bfg = bb[HID + ac];
  const float bg = bb[2*HID + ac], bo = bb[3*HID + ac];
  float cst = c0[dir * HID + ac];

  __shared__ float hl[4][128];
  __shared__ float el[4][64];
  __shared__ float ps[2][4][2][64];

  // prefetch emb quarter for step 0
  float epf;
  {
    const int tt0 = dir ? (T_LEN - 1) : 0;
    epf = embed[(size_t)x[tt0] * EMB + w * 64 + l];
  }

  unsigned spins = 0;

  for (int t = 0; t < T_LEN; ++t) {
    const int par = t & 1;
    const int tt  = dir ? (T_LEN - 1 - t) : t;

    // issue this wave's 2-pair poll early (in flight during emb work)
    unsigned long long* psrc = pb + ((par ^ 1) * 512) + w * 128 + 2 * l;
    uint4v fpr;
    unsigned long long sp0 = 0, sp1 = 0;
    if (FAST) {
      issue_ld4_sc0(psrc, fpr);
    } else {
      sp0 = ld_pair_agent(&psrc[0]);
      sp1 = ld_pair_agent(&psrc[1]);
    }

    // stage emb quarter (intra-wave only)
    el[w][l] = epf;
    __builtin_amdgcn_wave_barrier();
    asm volatile("s_waitcnt lgkmcnt(0)" ::: "memory");
    __builtin_amdgcn_sched_barrier(0);

    // emb contribution overlaps the poll latency (chain order == round 3)
    float acc0 = 0.f, acc1 = 0.f;
    {
      const float* eseg = el[w];
      #pragma unroll
      for (int i = 0; i < 16; ++i) {
        float4 ev = *(const float4*)&eseg[i*4];
        acc0 += we0[i*4+0]*ev.x + we0[i*4+1]*ev.y + we0[i*4+2]*ev.z + we0[i*4+3]*ev.w;
        acc1 += we1[i*4+0]*ev.x + we1[i*4+1]*ev.y + we1[i*4+2]*ev.z + we1[i*4+3]*ev.w;
      }
    }

    // spin until this wave's chunk carries tag t+1 (h_{t-1})
    const unsigned tgt = (unsigned)(t + 1);
    if (FAST) {
      wait_ld(fpr);
      for (;;) {
        if (__all((fpr.y == tgt) && (fpr.w == tgt))) break;
        if (++spins > 4000000u) break;   // safety valve
        issue_ld4_sc0(psrc, fpr);
        wait_ld(fpr);
      }
    } else {
      for (;;) {
        const bool f = ((unsigned)(sp0 >> 32) == tgt) && ((unsigned)(sp1 >> 32) == tgt);
        if (__all(f)) break;
        if (++spins > 4000000u) break;
        __builtin_amdgcn_s_sleep(1);
        sp0 = ld_pair_agent(&psrc[0]);
        sp1 = ld_pair_agent(&psrc[1]);
      }
    }

    // polled chunk -> per-wave LDS
    {
      float2 hv2;
      if (FAST) { hv2.x = __uint_as_float(fpr.x); hv2.y = __uint_as_float(fpr.z); }
      else      { hv2.x = __uint_as_float((unsigned)sp0); hv2.y = __uint_as_float((unsigned)sp1); }
      *(float2*)&hl[w][2*l] = hv2;
    }
    __builtin_amdgcn_wave_barrier();
    asm volatile("s_waitcnt lgkmcnt(0)" ::: "memory");
    __builtin_amdgcn_sched_barrier(0);

    // h contribution (same-address quads broadcast, conflict-free)
    {
      const float* hseg = hl[w];
      #pragma unroll
      for (int i = 0; i < 32; ++i) {
        float4 hv = *(const float4*)&hseg[i*4];
        acc0 += wh0[i*4+0]*hv.x + wh0[i*4+1]*hv.y + wh0[i*4+2]*hv.z + wh0[i*4+3]*hv.w;
        acc1 += wh1[i*4+0]*hv.x + wh1[i*4+1]*hv.y + wh1[i*4+2]*hv.z + wh1[i*4+3]*hv.w;
      }
    }

    ps[par][w][0][l] = acc0;
    ps[par][w][1][l] = acc1;
    __syncthreads();   // the one per-step intra-WG join

    if (w == 0) {
      const float t0 = (ps[par][0][0][l] + ps[par][1][0][l])
                     + (ps[par][2][0][l] + ps[par][3][0][l]);   // round-3 tree
      const float t1 = (ps[par][0][1][l] + ps[par][1][1][l])
                     + (ps[par][2][1][l] + ps[par][3][1][l]);
      const float a0 = __shfl(t0, jl),      b0 = __shfl(t1, jl);
      const float a1 = __shfl(t0, 16 + jl), b1 = __shfl(t1, 16 + jl);
      const float a2 = __shfl(t0, 32 + jl), b2 = __shfl(t1, 32 + jl);
      const float a3 = __shfl(t0, 48 + jl), b3 = __shfl(t1, 48 + jl);
      if (l < 32) {
        const bool hi = (l & 16) != 0;
        const float gi_ = (hi ? b0 : a0) + bi;
        const float gf_ = (hi ? b1 : a1) + bfg;
        const float gg_ = (hi ? b2 : a2) + bg;
        const float go_ = (hi ? b3 : a3) + bo;
        const float si = 1.f / (1.f + expf(-gi_));
        const float sf = 1.f / (1.f + expf(-gf_));
        const float so = 1.f / (1.f + expf(-go_));
        const float cn = sf * cst + si * tanhf(gg_);
        cst = cn;
        const float hv = so * tanhf(cn);
        const unsigned long long pk = packph(hv, (unsigned)(t + 2));
        if (FAST) st_pair_sc0(&pb[par * 512 + J0 + l], pk);
        else      st_pair_agent(&pb[par * 512 + J0 + l], pk);
        hOut[((size_t)dir * T_LEN + tt) * HID + J0 + l] = hv;
      }
    }

    // prefetch next emb quarter (hides under next step's poll)
    if (t + 1 < T_LEN) {
      const int ttn = dir ? (T_LEN - 2 - t) : (t + 1);
      epf = embed[(size_t)x[ttn] * EMB + w * 64 + l];
    }
  }
}

// ---------------------------------------------------------------------------
// Election + verified-sc0 / agent-fallback dispatcher. All spins bounded;
// correctness never depends on placement, XCC_ID truth, or sc0 semantics.
// ---------------------------------------------------------------------------
__global__ __launch_bounds__(256, 1) void lstm_kernel(
    const float* __restrict__ Whh_f, const float* __restrict__ Whh_b,
    const float* __restrict__ Wih_f, const float* __restrict__ Wih_b,
    const float* __restrict__ b_f,  const float* __restrict__ b_b,
    const float* __restrict__ h0,   const float* __restrict__ c0,
    const int*   __restrict__ x,    const float* __restrict__ embed,
    unsigned long long* __restrict__ pairs,    // sc0-mode pair buffer
    unsigned long long* __restrict__ pairs2,   // agent-mode pair buffer
    float* __restrict__ hOut, int* __restrict__ elect)
{
  const int tid = threadIdx.x;
  __shared__ int s_slot, s_mode;
  __shared__ int s_ok[4];

  // ---- phase 1: census + choose + claim (tid 0) ----
  if (tid == 0) {
    int xcc;
    asm volatile("s_getreg_b32 %0, hwreg(HW_REG_XCC_ID)" : "=s"(xcc));
    xcc &= 7;
    __hip_atomic_fetch_add(&elect[E_CENSUS + xcc], 1, __ATOMIC_RELAXED, __HIP_MEMORY_SCOPE_AGENT);
    const int a = __hip_atomic_fetch_add(&elect[E_ARRIVE], 1, __ATOMIC_ACQ_REL, __HIP_MEMORY_SCOPE_AGENT);
    if (a == NLAUNCH - 1) {
      int best = 0, bc = -1;
      for (int i = 0; i < 8; ++i) {
        const int ci = __hip_atomic_load(&elect[E_CENSUS + i], __ATOMIC_RELAXED, __HIP_MEMORY_SCOPE_AGENT);
        if (ci > bc) { bc = ci; best = i; }
      }
      __hip_atomic_store(&elect[E_CHOSEN], best + 1, __ATOMIC_RELEASE, __HIP_MEMORY_SCOPE_AGENT);
    }
    int ch = 0;
    for (unsigned g = 0; g < 300000u; ++g) {
      ch = __hip_atomic_load(&elect[E_CHOSEN], __ATOMIC_ACQUIRE, __HIP_MEMORY_SCOPE_AGENT);
      if (ch) break;
      __builtin_amdgcn_s_sleep(2);
    }
    int slot = -1;
    if (ch == 0 || ch - 1 == xcc) {    // ch==0: degraded, claim anyway (agent mode will win)
      const int cl = __hip_atomic_fetch_add(&elect[E_CLAIM], 1, __ATOMIC_RELAXED, __HIP_MEMORY_SCOPE_AGENT);
      if (cl < NTEAM) slot = cl;
    }
    if (slot >= 0)
      __hip_atomic_store(&elect[E_XCC + slot], xcc + 1, __ATOMIC_RELEASE, __HIP_MEMORY_SCOPE_AGENT);
    s_slot = slot;
  }
  __syncthreads();
  const int slot = s_slot;
  if (slot < 0) return;   // not on the team

  const int dir = slot >> 4;
  const int sl  = slot & 15;
  const int J0  = sl * 32;
  const int w   = tid >> 6;
  const int l   = tid & 63;

  // ---- phase 2: membership + XCC uniformity (provisional mode) ----
  if (tid == 0) {
    int uni = 0;
    for (unsigned g = 0; g < 60000u; ++g) {
      int allnz = 1;
      for (int i = 0; i < NTEAM; ++i)
        if (!__hip_atomic_load(&elect[E_XCC + i], __ATOMIC_ACQUIRE, __HIP_MEMORY_SCOPE_AGENT)) { allnz = 0; break; }
      if (allnz) { uni = 1; break; }
      __builtin_amdgcn_s_sleep(2);
    }
    if (uni) {
      const int v0 = __hip_atomic_load(&elect[E_XCC], __ATOMIC_RELAXED, __HIP_MEMORY_SCOPE_AGENT);
      for (int i = 1; i < NTEAM; ++i)
        if (__hip_atomic_load(&elect[E_XCC + i], __ATOMIC_RELAXED, __HIP_MEMORY_SCOPE_AGENT) != v0) { uni = 0; break; }
    }
    s_mode = uni;
  }
  __syncthreads();

  // ---- phase 3: sc0 handshake (exact main-loop access pattern) + vote ----
  if (s_mode) {
    if (w == 0 && l < 32)
      st_pair_sc0(&pairs[(size_t)dir * 1024 + 512 + J0 + l],
                  packph(h0[dir * HID + J0 + l], 1u));
    int okw = 0;
    {
      const unsigned long long* hp = pairs + (size_t)dir * 1024 + 512 + w * 128 + 2 * l;
      uint4v pr;
      for (unsigned g = 0; g < 50000u; ++g) {
        issue_ld4_sc0(hp, pr);
        wait_ld(pr);
        if (__all((pr.y == 1u) && (pr.w == 1u))) { okw = 1; break; }
      }
    }
    if (l == 0) s_ok[w] = okw;
    __syncthreads();
    if (tid == 0) {
      const int ok = s_ok[0] & s_ok[1] & s_ok[2] & s_ok[3];
      __hip_atomic_fetch_add(&elect[E_VOTE], ok ? 1 : 0x10000, __ATOMIC_ACQ_REL, __HIP_MEMORY_SCOPE_AGENT);
      int v = 0;
      for (unsigned g = 0; g < 300000u; ++g) {
        v = __hip_atomic_load(&elect[E_VOTE], __ATOMIC_ACQUIRE, __HIP_MEMORY_SCOPE_AGENT);
        if ((v & 0xffff) + (v >> 16) >= NTEAM) break;
        __builtin_amdgcn_s_sleep(2);
      }
      s_mode = ((v >> 16) == 0 && (v & 0xffff) >= NTEAM) ? 1 : 0;
    }
    __syncthreads();
  }
  const int mode = s_mode;

  if (!mode) {   // agent fallback: fresh buffer, republish h_{-1}
    if (w == 0 && l < 32)
      st_pair_agent(&pairs2[(size_t)dir * 1024 + 512 + J0 + l],
                    packph(h0[dir * HID + J0 + l], 1u));
  }

  const float* Whh = dir ? Whh_b : Whh_f;
  const float* Wih = dir ? Wih_b : Wih_f;
  const float* bb  = dir ? b_b  : b_f;

  if (mode)
    lstm_body<1>(Whh, Wih, bb, c0, x, embed, pairs  + (size_t)dir * 1024, hOut, dir, sl, w, l);
  else
    lstm_body<0>(Whh, Wih, bb, c0, x, embed, pairs2 + (size_t)dir * 1024, hOut, dir, sl, w, l);
}

// ---------------------------------------------------------------------------
// feats[t][k] = concat(hf[t], hb[t]) . fc_w[k] + fc_b[k]
// ---------------------------------------------------------------------------
__global__ __launch_bounds__(256) void feats_kernel(
    const float* __restrict__ hOut, const float* __restrict__ fc_w,
    const float* __restrict__ fc_b, float* __restrict__ feats)
{
  const int tid = threadIdx.x;
  const int k   = tid & 15;
  const int tl  = tid >> 4;
  const int t   = blockIdx.x * 16 + tl;
  const float* hf = hOut + (size_t)t * HID;
  const float* hb = hOut + ((size_t)T_LEN + t) * HID;
  const float* wr = fc_w + (size_t)k * (2 * HID);
  float acc = fc_b[k];
  #pragma unroll 4
  for (int j = 0; j < HID; j += 4) {
    float4 hv = *(const float4*)&hf[j];
    float4 wv = *(const float4*)&wr[j];
    acc += hv.x*wv.x + hv.y*wv.y + hv.z*wv.z + hv.w*wv.w;
  }
  #pragma unroll 4
  for (int j = 0; j < HID; j += 4) {
    float4 hv = *(const float4*)&hb[j];
    float4 wv = *(const float4*)&wr[HID + j];
    acc += hv.x*wv.x + hv.y*wv.y + hv.z*wv.z + hv.w*wv.w;
  }
  feats[(size_t)t * KTAG + k] = acc;
}

// ---------------------------------------------------------------------------
// Viterbi: single block. DP state vl kept in wave-0 REGISTERS (lane 4n holds
// vl[n]); gathers via __shfl — no per-step LDS round trip. First-max tie
// rules preserved exactly. Backtrack via per-64-step chunk maps.
// ---------------------------------------------------------------------------
__global__ __launch_bounds__(256) void viterbi_kernel(
    const float* __restrict__ feats, const float* __restrict__ trans,
    float* __restrict__ out)
{
  __shared__ float fch[256 * KTAG];           // 16 KB feats chunk
  __shared__ unsigned char bps8[T_LEN * 8];   // 32 KB packed backpointers
  __shared__ unsigned char ml[64 * 16];       // chunk maps
  __shared__ unsigned char rb[64];            // chunk right-boundary tags
  __shared__ int sbest;

  const int tid  = threadIdx.x;
  const int lane = tid & 63;
  const int nxt  = lane >> 2;
  const int pg   = lane & 3;

  float tr[4] = {0.f, 0.f, 0.f, 0.f};
  if (tid < 64) {
    #pragma unroll
    for (int p = 0; p < 4; ++p)
      tr[p] = trans[nxt * KTAG + pg * 4 + p];
  }
  // vl in registers: lane 4n holds vl[n]
  float vlreg = ((lane >> 2) == START_TAG) ? 0.f : NEGV;
  __syncthreads();

  for (int ch = 0; ch < 16; ++ch) {
    const float* src = feats + (size_t)ch * 256 * KTAG;
    #pragma unroll
    for (int i = 0; i < 4; ++i)
      *(float4*)&fch[(i * 256 + tid) * 4] = *(const float4*)&src[(i * 256 + tid) * 4];
    __syncthreads();

    if (tid < 64) {
      const int sbase = pg << 4;
      for (int tl = 0; tl < 256; ++tl) {
        const int t = ch * 256 + tl;
        const float s0 = __shfl(vlreg, sbase);
        const float s1 = __shfl(vlreg, sbase + 4);
        const float s2 = __shfl(vlreg, sbase + 8);
        const float s3 = __shfl(vlreg, sbase + 12);
        float best = s0 + tr[0]; int bp = pg * 4;
        float sc = s1 + tr[1]; if (sc > best) { best = sc; bp = pg * 4 + 1; }
        sc = s2 + tr[2]; if (sc > best) { best = sc; bp = pg * 4 + 2; }
        sc = s3 + tr[3]; if (sc > best) { best = sc; bp = pg * 4 + 3; }
        #pragma unroll
        for (int m = 1; m <= 2; m <<= 1) {      // merge groups, prefer lower idx
          const float ob = __shfl_xor(best, m);
          const int  obp = __shfl_xor(bp, m);
          if (ob > best || (ob == best && obp < bp)) { best = ob; bp = obp; }
        }
        const int nbp = __shfl(bp, (lane + 4) & 63);  // neighbor next's bp
        if (pg == 0 && (nxt & 1) == 0)
          bps8[t * 8 + (nxt >> 1)] = (unsigned char)(bp | (nbp << 4));
        const float fv = fch[tl * KTAG + nxt];
        vlreg = (pg == 0) ? (best + fv) : vlreg;
      }
    }
    __syncthreads();
  }

  if (tid < 64) {
    const float vfin = __shfl(vlreg, (lane & 15) << 2);
    float term = (lane < KTAG) ? (vfin + trans[END_TAG * KTAG + lane]) : -3.0e38f;
    int bt = (lane < KTAG) ? lane : KTAG;
    #pragma unroll
    for (int m = 1; m < 64; m <<= 1) {
      const float ot = __shfl_xor(term, m);
      const int  obt = __shfl_xor(bt, m);
      if (ot > term || (ot == term && obt < bt)) { term = ot; bt = obt; }
    }
    if (lane == 0) { out[0] = term; sbest = bt; }
  }
  __syncthreads();

  if (tid < 64) {
    const int L = lane;
    unsigned char cur[16];
    #pragma unroll
    for (int g = 0; g < 16; ++g) cur[g] = (unsigned char)g;
    for (int i = 63; i >= 0; --i) {
      const int t = L * 64 + i;
      #pragma unroll
      for (int g = 0; g < 16; ++g) {
        const unsigned char cc = cur[g];
        const unsigned char by = bps8[t * 8 + (cc >> 1)];
        cur[g] = (cc & 1) ? (by >> 4) : (by & 15);
      }
    }
    #pragma unroll
    for (int g = 0; g < 16; ++g) ml[L * 16 + g] = cur[g];
  }
  __syncthreads();

  if (tid == 0) {
    int r = sbest;
    rb[63] = (unsigned char)r;
    for (int cix = 62; cix >= 0; --cix) {
      r = ml[(cix + 1) * 16 + r];
      rb[cix] = (unsigned char)r;
    }
  }
  __syncthreads();

  if (tid < 64) {
    const int L = lane;
    int tag = rb[L];
    out[1 + L * 64 + 63] = (float)tag;
    for (int i = 62; i >= 0; --i) {
      const int t = L * 64 + i + 1;
      const unsigned char by = bps8[t * 8 + (tag >> 1)];
      tag = (tag & 1) ? (by >> 4) : (by & 15);
      out[1 + L * 64 + i] = (float)tag;
    }
  }
}

// ---------------------------------------------------------------------------
extern "C" void kernel_launch(void* const* d_in, const int* in_sizes, int n_in,
                              void* d_out, int out_size, void* d_ws, size_t ws_size,
                              hipStream_t stream) {
  (void)in_sizes; (void)n_in; (void)out_size; (void)ws_size;
  const int*   x      = (const int*)  d_in[0];
  const float* h0     = (const float*)d_in[1];
  const float* c0     = (const float*)d_in[2];
  const float* embed  = (const float*)d_in[3];
  const float* Wih_f  = (const float*)d_in[4];
  const float* Whh_f  = (const float*)d_in[5];
  const float* b_f    = (const float*)d_in[6];
  const float* Wih_b  = (const float*)d_in[7];
  const float* Whh_b  = (const float*)d_in[8];
  const float* b_b    = (const float*)d_in[9];
  const float* fc_w   = (const float*)d_in[10];
  const float* fc_b   = (const float*)d_in[11];
  const float* trans  = (const float*)d_in[12];
  float* out = (float*)d_out;

  char* ws = (char*)d_ws;
  unsigned long long* pairs  = (unsigned long long*)(ws + 0);      // 16 KB
  unsigned long long* pairs2 = (unsigned long long*)(ws + 16384);  // 16 KB
  int*   elect    = (int*)(ws + 32768);                            // 256 B
  float* feats    = (float*)(ws + 65536);                          // 256 KB
  float* hOut     = (float*)(ws + (1ull << 20));                   // 16 MB

  // zero pair tags (both buffers) + election state each launch
  hipMemsetAsync(ws, 0, 36864, stream);

  {
    void* args[] = {
      (void*)&Whh_f, (void*)&Whh_b, (void*)&Wih_f, (void*)&Wih_b,
      (void*)&b_f,   (void*)&b_b,   (void*)&h0,    (void*)&c0,
      (void*)&x,     (void*)&embed, (void*)&pairs, (void*)&pairs2,
      (void*)&hOut,  (void*)&elect
    };
    hipLaunchCooperativeKernel((const void*)lstm_kernel, dim3(NLAUNCH), dim3(256),
                               args, 0, stream);
  }

  feats_kernel<<<dim3(T_LEN / 16), 256, 0, stream>>>(hOut, fc_w, fc_b, feats);
  viterbi_kernel<<<dim3(1), 256, 0, stream>>>(feats, trans, out);
}